// Round 1
// baseline (938.018 us; speedup 1.0000x reference)
//
#include <hip/hip_runtime.h>
#include <math.h>

#define D 64

// Detect whether edge_index is int64 (little-endian: odd int32 words are the
// zero high-halves, since all indices < 2^31) or int32 (odd words are random
// node ids, essentially never all zero across 64 samples).
__global__ void detect_idx64(const int* __restrict__ ei, int* __restrict__ flag) {
    int v = ei[2 * threadIdx.x + 1];
    unsigned long long b = __ballot(v != 0);
    if (threadIdx.x == 0) flag[0] = (b == 0ULL) ? 1 : 0;
}

// One wave (64 lanes) per edge: lane i handles feature i.
// Coalesced 256B gather of x[src], 64 consecutive f32 atomics into agg[dst].
__global__ __launch_bounds__(256) void sage_scatter(
        const float* __restrict__ x,
        const void* __restrict__ eidx,
        const int* __restrict__ flagp,
        float* __restrict__ agg,
        float* __restrict__ deg,
        int nE, int doDeg) {
    const bool idx64 = (*flagp != 0);
    const int lane = threadIdx.x & 63;
    int wave = (int)((blockIdx.x * blockDim.x + threadIdx.x) >> 6);
    const int waveStride = (int)((gridDim.x * blockDim.x) >> 6);
    const int* __restrict__ ei32 = (const int*)eidx;
    const long long* __restrict__ ei64 = (const long long*)eidx;
    for (int e = wave; e < nE; e += waveStride) {
        int s, d;
        if (idx64) { s = (int)ei64[e]; d = (int)ei64[e + nE]; }
        else       { s = ei32[e];      d = ei32[e + nE]; }
        atomicAdd(&agg[(size_t)d * D + lane], x[(size_t)s * D + lane]);
        if (doDeg && lane == 0) atomicAdd(&deg[d], 1.0f);
    }
}

// Per-node update: out = (agg/max(deg,1)) @ wl^T + bl + xin @ wr^T,
// then ReLU (mode 0) or row L2-normalize (mode 1).
// Weights staged transposed in LDS: wlT[k*64+f] = wl[f*64+k] so the
// lane-varying index f walks banks (2-way alias = free on CDNA4).
__global__ __launch_bounds__(256) void sage_update(
        const float* __restrict__ xin,
        const float* __restrict__ agg,
        const float* __restrict__ deg,
        const float* __restrict__ wl,
        const float* __restrict__ bl,
        const float* __restrict__ wr,
        float* __restrict__ xout,
        int nNodes, int mode) {
    __shared__ float wlT[D * D];
    __shared__ float wrT[D * D];
    __shared__ float rowA[4][D];
    __shared__ float rowX[4][D];
    for (int i = threadIdx.x; i < D * D; i += blockDim.x) {
        int f = i >> 6, k = i & 63;
        wlT[k * D + f] = wl[i];
        wrT[k * D + f] = wr[i];
    }
    __syncthreads();
    const int lane = threadIdx.x & 63;
    const int wid = threadIdx.x >> 6;   // 4 waves per block, one node per wave
    const float blv = bl[lane];
    for (int node = blockIdx.x * 4 + wid; node < nNodes; node += gridDim.x * 4) {
        float dg = fmaxf(deg[node], 1.0f);
        float a  = agg[(size_t)node * D + lane] / dg;
        float xv = xin[(size_t)node * D + lane];
        // stage rows for wave-internal broadcast (single-wave producer/consumer,
        // no barrier needed; compiler inserts lgkmcnt waits)
        rowA[wid][lane] = a;
        rowX[wid][lane] = xv;
        float acc = blv;
        #pragma unroll
        for (int k = 0; k < D; ++k) {
            acc = fmaf(rowA[wid][k], wlT[k * D + lane], acc);
            acc = fmaf(rowX[wid][k], wrT[k * D + lane], acc);
        }
        if (mode == 0) {
            xout[(size_t)node * D + lane] = fmaxf(acc, 0.0f);
        } else {
            float ss = acc * acc;
            #pragma unroll
            for (int off = 32; off >= 1; off >>= 1)
                ss += __shfl_xor(ss, off, 64);
            xout[(size_t)node * D + lane] = acc / fmaxf(sqrtf(ss), 1e-12f);
        }
    }
}

extern "C" void kernel_launch(void* const* d_in, const int* in_sizes, int n_in,
                              void* d_out, int out_size, void* d_ws, size_t ws_size,
                              hipStream_t stream) {
    const float* x   = (const float*)d_in[0];
    const float* wl0 = (const float*)d_in[1];
    const float* bl0 = (const float*)d_in[2];
    const float* wr0 = (const float*)d_in[3];
    const float* wl1 = (const float*)d_in[4];
    const float* bl1 = (const float*)d_in[5];
    const float* wr1 = (const float*)d_in[6];
    const void*  ei  = d_in[7];
    float* out = (float*)d_out;

    const int N = in_sizes[0] / D;
    const int E = in_sizes[7] / 2;

    char* ws = (char*)d_ws;
    int*   flag = (int*)ws;                                   // 256 B slot
    float* deg  = (float*)(ws + 256);                         // N f32
    size_t degB = (((size_t)N * 4) + 255) & ~(size_t)255;
    float* agg  = (float*)(ws + 256 + degB);                  // N*64 f32
    float* x1   = out;  // layer-0 output lives in d_out; layer-1 update is
                        // safely in-place (each row read-before-write by its own wave)

    detect_idx64<<<1, 64, 0, stream>>>((const int*)ei, flag);

    // zero deg + agg in one contiguous memset
    hipMemsetAsync(deg, 0, degB + (size_t)N * D * 4, stream);
    sage_scatter<<<4096, 256, 0, stream>>>(x, ei, flag, agg, deg, E, 1);
    sage_update<<<2048, 256, 0, stream>>>(x, agg, deg, wl0, bl0, wr0, x1, N, 0);

    hipMemsetAsync(agg, 0, (size_t)N * D * 4, stream);
    sage_scatter<<<4096, 256, 0, stream>>>(x1, ei, flag, agg, deg, E, 0);
    sage_update<<<2048, 256, 0, stream>>>(x1, agg, deg, wl1, bl1, wr1, out, N, 1);
}

// Round 3
// 749.056 us; speedup vs baseline: 1.2523x; 1.2523x over previous
//
#include <hip/hip_runtime.h>
#include <math.h>

#define D 64
#define CHUNK 1024   // elements scanned per block (256 thr x 4)

// Detect whether edge_index is int64 (odd int32 words are zero high-halves)
// or int32 (odd words are random node ids).
__global__ void detect_idx64(const int* __restrict__ ei, int* __restrict__ flag) {
    int v = ei[2 * threadIdx.x + 1];
    unsigned long long b = __ballot(v != 0);
    if (threadIdx.x == 0) flag[0] = (b == 0ULL) ? 1 : 0;
}

// ---------------- CSR build ----------------

__global__ __launch_bounds__(256) void edge_hist(
        const void* __restrict__ eidx, const int* __restrict__ flagp,
        int* __restrict__ counts, int nE) {
    const bool idx64 = (*flagp != 0);
    const int* __restrict__ ei32 = (const int*)eidx;
    const long long* __restrict__ ei64 = (const long long*)eidx;
    int i = blockIdx.x * blockDim.x + threadIdx.x;
    int stride = gridDim.x * blockDim.x;
    for (int e = i; e < nE; e += stride) {
        int d = idx64 ? (int)ei64[e + nE] : ei32[e + nE];
        atomicAdd(&counts[d], 1);
    }
}

__global__ __launch_bounds__(256) void scan_partial(
        const int* __restrict__ counts, int* __restrict__ blockSums, int n) {
    __shared__ int red[4];
    int base = blockIdx.x * CHUNK + threadIdx.x * 4;
    int s = 0;
    #pragma unroll
    for (int k = 0; k < 4; ++k) { int i = base + k; if (i < n) s += counts[i]; }
    #pragma unroll
    for (int off = 32; off >= 1; off >>= 1) s += __shfl_xor(s, off, 64);
    int lane = threadIdx.x & 63, wid = threadIdx.x >> 6;
    if (lane == 0) red[wid] = s;
    __syncthreads();
    if (threadIdx.x == 0) blockSums[blockIdx.x] = red[0] + red[1] + red[2] + red[3];
}

// Exclusive scan of blockSums (nB <= 256) in one block; writes total -> rowStartN.
__global__ __launch_bounds__(256) void scan_block(
        const int* __restrict__ blockSums, int* __restrict__ blockOffsets,
        int* __restrict__ rowStartN, int nB) {
    __shared__ int wtot[4];
    int tid = threadIdx.x, lane = tid & 63, wid = tid >> 6;
    int v = (tid < nB) ? blockSums[tid] : 0;
    int x = v;
    #pragma unroll
    for (int off = 1; off < 64; off <<= 1) { int y = __shfl_up(x, off, 64); if (lane >= off) x += y; }
    if (lane == 63) wtot[wid] = x;
    __syncthreads();
    int woff = 0;
    for (int w = 0; w < wid; ++w) woff += wtot[w];
    if (tid < nB) blockOffsets[tid] = woff + x - v;
    if (tid == 255) rowStartN[0] = woff + x;   // grand total = E
}

// Block-level exclusive scan with global offset; writes rowStart and cursor.
// NOTE: cursor may alias counts — every thread reads its 4 counts into
// registers before any write, and element ownership is 1 thread : 4 elems.
__global__ __launch_bounds__(256) void scan_final(
        const int* __restrict__ counts, const int* __restrict__ blockOffsets,
        int* __restrict__ rowStart, int* __restrict__ cursor, int n) {
    __shared__ int wtot[4];
    int tid = threadIdx.x, lane = tid & 63, wid = tid >> 6;
    int base = blockIdx.x * CHUNK + tid * 4;
    int v0 = (base + 0 < n) ? counts[base + 0] : 0;
    int v1 = (base + 1 < n) ? counts[base + 1] : 0;
    int v2 = (base + 2 < n) ? counts[base + 2] : 0;
    int v3 = (base + 3 < n) ? counts[base + 3] : 0;
    int t = v0 + v1 + v2 + v3;
    int x = t;
    #pragma unroll
    for (int off = 1; off < 64; off <<= 1) { int y = __shfl_up(x, off, 64); if (lane >= off) x += y; }
    if (lane == 63) wtot[wid] = x;
    __syncthreads();
    int woff = 0;
    for (int w = 0; w < wid; ++w) woff += wtot[w];
    int e = blockOffsets[blockIdx.x] + woff + (x - t);
    if (base + 0 < n) { rowStart[base + 0] = e; cursor[base + 0] = e; } e += v0;
    if (base + 1 < n) { rowStart[base + 1] = e; cursor[base + 1] = e; } e += v1;
    if (base + 2 < n) { rowStart[base + 2] = e; cursor[base + 2] = e; } e += v2;
    if (base + 3 < n) { rowStart[base + 3] = e; cursor[base + 3] = e; }
}

__global__ __launch_bounds__(256) void edge_fill(
        const void* __restrict__ eidx, const int* __restrict__ flagp,
        int* __restrict__ cursor, int* __restrict__ srcs, int nE) {
    const bool idx64 = (*flagp != 0);
    const int* __restrict__ ei32 = (const int*)eidx;
    const long long* __restrict__ ei64 = (const long long*)eidx;
    int i = blockIdx.x * blockDim.x + threadIdx.x;
    int stride = gridDim.x * blockDim.x;
    for (int e = i; e < nE; e += stride) {
        int s, d;
        if (idx64) { s = (int)ei64[e]; d = (int)ei64[e + nE]; }
        else       { s = ei32[e];      d = ei32[e + nE]; }
        int pos = atomicAdd(&cursor[d], 1);
        srcs[pos] = s;
    }
}

// Fused mean-aggregate + linear update. One wave per node, lane = feature.
// xin and xout MUST NOT alias (neighbor rows of xin are read while xout rows
// are written by other waves).
__global__ __launch_bounds__(256) void sage_layer(
        const float* __restrict__ x,
        const int* __restrict__ rowStart,
        const int* __restrict__ srcs,
        const float* __restrict__ wl,
        const float* __restrict__ bl,
        const float* __restrict__ wr,
        float* __restrict__ xout,
        int nNodes, int mode) {
    __shared__ float wlT[D * D];
    __shared__ float wrT[D * D];
    __shared__ float rowA[4][D];
    __shared__ float rowX[4][D];
    for (int i = threadIdx.x; i < D * D; i += blockDim.x) {
        int f = i >> 6, k = i & 63;
        wlT[k * D + f] = wl[i];
        wrT[k * D + f] = wr[i];
    }
    __syncthreads();
    const int lane = threadIdx.x & 63;
    const int wid = threadIdx.x >> 6;
    const float blv = bl[lane];
    for (int node = blockIdx.x * 4 + wid; node < nNodes; node += gridDim.x * 4) {
        int r0 = rowStart[node], r1 = rowStart[node + 1];
        float acc = 0.0f;
        int j = r0;
        for (; j + 4 <= r1; j += 4) {
            int s0 = srcs[j], s1 = srcs[j + 1], s2 = srcs[j + 2], s3 = srcs[j + 3];
            acc += x[(size_t)s0 * D + lane];
            acc += x[(size_t)s1 * D + lane];
            acc += x[(size_t)s2 * D + lane];
            acc += x[(size_t)s3 * D + lane];
        }
        for (; j < r1; ++j) acc += x[(size_t)srcs[j] * D + lane];
        float a  = acc / fmaxf((float)(r1 - r0), 1.0f);
        float xv = x[(size_t)node * D + lane];
        rowA[wid][lane] = a;
        rowX[wid][lane] = xv;
        float o = blv;
        #pragma unroll
        for (int k = 0; k < D; ++k) {
            o = fmaf(rowA[wid][k], wlT[k * D + lane], o);
            o = fmaf(rowX[wid][k], wrT[k * D + lane], o);
        }
        if (mode == 0) {
            xout[(size_t)node * D + lane] = fmaxf(o, 0.0f);
        } else {
            float ss = o * o;
            #pragma unroll
            for (int off = 32; off >= 1; off >>= 1) ss += __shfl_xor(ss, off, 64);
            xout[(size_t)node * D + lane] = o / fmaxf(sqrtf(ss), 1e-12f);
        }
    }
}

// ---------------- fallback: atomic scatter path (round-1, known-correct) ----

__global__ __launch_bounds__(256) void sage_scatter(
        const float* __restrict__ x,
        const void* __restrict__ eidx,
        const int* __restrict__ flagp,
        float* __restrict__ agg,
        float* __restrict__ deg,
        int nE, int doDeg) {
    const bool idx64 = (*flagp != 0);
    const int lane = threadIdx.x & 63;
    int wave = (int)((blockIdx.x * blockDim.x + threadIdx.x) >> 6);
    const int waveStride = (int)((gridDim.x * blockDim.x) >> 6);
    const int* __restrict__ ei32 = (const int*)eidx;
    const long long* __restrict__ ei64 = (const long long*)eidx;
    for (int e = wave; e < nE; e += waveStride) {
        int s, d;
        if (idx64) { s = (int)ei64[e]; d = (int)ei64[e + nE]; }
        else       { s = ei32[e];      d = ei32[e + nE]; }
        atomicAdd(&agg[(size_t)d * D + lane], x[(size_t)s * D + lane]);
        if (doDeg && lane == 0) atomicAdd(&deg[d], 1.0f);
    }
}

__global__ __launch_bounds__(256) void sage_update(
        const float* __restrict__ xin,
        const float* __restrict__ agg,
        const float* __restrict__ deg,
        const float* __restrict__ wl,
        const float* __restrict__ bl,
        const float* __restrict__ wr,
        float* __restrict__ xout,
        int nNodes, int mode) {
    __shared__ float wlT[D * D];
    __shared__ float wrT[D * D];
    __shared__ float rowA[4][D];
    __shared__ float rowX[4][D];
    for (int i = threadIdx.x; i < D * D; i += blockDim.x) {
        int f = i >> 6, k = i & 63;
        wlT[k * D + f] = wl[i];
        wrT[k * D + f] = wr[i];
    }
    __syncthreads();
    const int lane = threadIdx.x & 63;
    const int wid = threadIdx.x >> 6;
    const float blv = bl[lane];
    for (int node = blockIdx.x * 4 + wid; node < nNodes; node += gridDim.x * 4) {
        float dg = fmaxf(deg[node], 1.0f);
        float a  = agg[(size_t)node * D + lane] / dg;
        float xv = xin[(size_t)node * D + lane];
        rowA[wid][lane] = a;
        rowX[wid][lane] = xv;
        float acc = blv;
        #pragma unroll
        for (int k = 0; k < D; ++k) {
            acc = fmaf(rowA[wid][k], wlT[k * D + lane], acc);
            acc = fmaf(rowX[wid][k], wrT[k * D + lane], acc);
        }
        if (mode == 0) {
            xout[(size_t)node * D + lane] = fmaxf(acc, 0.0f);
        } else {
            float ss = acc * acc;
            #pragma unroll
            for (int off = 32; off >= 1; off >>= 1) ss += __shfl_xor(ss, off, 64);
            xout[(size_t)node * D + lane] = acc / fmaxf(sqrtf(ss), 1e-12f);
        }
    }
}

extern "C" void kernel_launch(void* const* d_in, const int* in_sizes, int n_in,
                              void* d_out, int out_size, void* d_ws, size_t ws_size,
                              hipStream_t stream) {
    const float* x   = (const float*)d_in[0];
    const float* wl0 = (const float*)d_in[1];
    const float* bl0 = (const float*)d_in[2];
    const float* wr0 = (const float*)d_in[3];
    const float* wl1 = (const float*)d_in[4];
    const float* bl1 = (const float*)d_in[5];
    const float* wr1 = (const float*)d_in[6];
    const void*  ei  = d_in[7];
    float* out = (float*)d_out;

    const int N = in_sizes[0] / D;
    const int E = in_sizes[7] / 2;
    const int nB = (N + CHUNK - 1) / CHUNK;   // 98 for N=100000 (<=256 required)

    char* ws = (char*)d_ws;
    size_t off = 0;
    auto alloc = [&](size_t bytes) { void* p = ws + off; off = (off + bytes + 255) & ~(size_t)255; return p; };

    // gather-path layout
    size_t need = 0;
    {
        size_t o = 0;
        auto sim = [&](size_t b) { o = (o + b + 255) & ~(size_t)255; };
        sim(4); sim((size_t)N * 4); sim(((size_t)N + 1) * 4);
        sim(256 * 4); sim(256 * 4); sim((size_t)E * 4); sim((size_t)N * D * 4);
        need = o;
    }

    if (ws_size >= need && nB <= 256) {
        int* flag         = (int*)alloc(4);
        int* counts       = (int*)alloc((size_t)N * 4);
        int* rowStart     = (int*)alloc(((size_t)N + 1) * 4);
        int* blockSums    = (int*)alloc(256 * 4);
        int* blockOffsets = (int*)alloc(256 * 4);
        int* srcs         = (int*)alloc((size_t)E * 4);
        float* x1         = (float*)alloc((size_t)N * D * 4);
        int* cursor = counts;   // aliased: counts dead after scan_final reads

        detect_idx64<<<1, 64, 0, stream>>>((const int*)ei, flag);
        hipMemsetAsync(counts, 0, (size_t)N * 4, stream);
        edge_hist<<<2048, 256, 0, stream>>>(ei, flag, counts, E);
        scan_partial<<<nB, 256, 0, stream>>>(counts, blockSums, N);
        scan_block<<<1, 256, 0, stream>>>(blockSums, blockOffsets, &rowStart[N], nB);
        scan_final<<<nB, 256, 0, stream>>>(counts, blockOffsets, rowStart, cursor, N);
        edge_fill<<<2048, 256, 0, stream>>>(ei, flag, cursor, srcs, E);

        sage_layer<<<8192, 256, 0, stream>>>(x,  rowStart, srcs, wl0, bl0, wr0, x1,  N, 0);
        sage_layer<<<8192, 256, 0, stream>>>(x1, rowStart, srcs, wl1, bl1, wr1, out, N, 1);
    } else {
        // fallback: round-1 scatter path (~26 MB ws)
        int*   flag = (int*)alloc(4);
        float* deg  = (float*)alloc((size_t)N * 4);
        float* agg  = (float*)alloc((size_t)N * D * 4);
        float* x1   = out;  // safe here: sage_update reads only its own row of xin

        detect_idx64<<<1, 64, 0, stream>>>((const int*)ei, flag);
        hipMemsetAsync(deg, 0, ((size_t)N + (size_t)N * D) * 4, stream);
        sage_scatter<<<4096, 256, 0, stream>>>(x, ei, flag, agg, deg, E, 1);
        sage_update<<<2048, 256, 0, stream>>>(x, agg, deg, wl0, bl0, wr0, x1, N, 0);
        hipMemsetAsync(agg, 0, (size_t)N * D * 4, stream);
        sage_scatter<<<4096, 256, 0, stream>>>(x1, ei, flag, agg, deg, E, 0);
        sage_update<<<2048, 256, 0, stream>>>(x1, agg, deg, wl1, bl1, wr1, out, N, 1);
    }
}

// Round 4
// 473.890 us; speedup vs baseline: 1.9794x; 1.5807x over previous
//
#include <hip/hip_runtime.h>
#include <math.h>

#define D 64
#define CHUNK 1024   // elements scanned per block (256 thr x 4)
#define GN 128       // nodes per gemm_update block

// Detect whether edge_index is int64 (odd int32 words are zero high-halves)
// or int32 (odd words are random node ids).
__global__ void detect_idx64(const int* __restrict__ ei, int* __restrict__ flag) {
    int v = ei[2 * threadIdx.x + 1];
    unsigned long long b = __ballot(v != 0);
    if (threadIdx.x == 0) flag[0] = (b == 0ULL) ? 1 : 0;
}

// ---------------- CSR build (unchanged from round 3, known-correct) --------

__global__ __launch_bounds__(256) void edge_hist(
        const void* __restrict__ eidx, const int* __restrict__ flagp,
        int* __restrict__ counts, int nE) {
    const bool idx64 = (*flagp != 0);
    const int* __restrict__ ei32 = (const int*)eidx;
    const long long* __restrict__ ei64 = (const long long*)eidx;
    int i = blockIdx.x * blockDim.x + threadIdx.x;
    int stride = gridDim.x * blockDim.x;
    for (int e = i; e < nE; e += stride) {
        int d = idx64 ? (int)ei64[e + nE] : ei32[e + nE];
        atomicAdd(&counts[d], 1);
    }
}

__global__ __launch_bounds__(256) void scan_partial(
        const int* __restrict__ counts, int* __restrict__ blockSums, int n) {
    __shared__ int red[4];
    int base = blockIdx.x * CHUNK + threadIdx.x * 4;
    int s = 0;
    #pragma unroll
    for (int k = 0; k < 4; ++k) { int i = base + k; if (i < n) s += counts[i]; }
    #pragma unroll
    for (int off = 32; off >= 1; off >>= 1) s += __shfl_xor(s, off, 64);
    int lane = threadIdx.x & 63, wid = threadIdx.x >> 6;
    if (lane == 0) red[wid] = s;
    __syncthreads();
    if (threadIdx.x == 0) blockSums[blockIdx.x] = red[0] + red[1] + red[2] + red[3];
}

__global__ __launch_bounds__(256) void scan_block(
        const int* __restrict__ blockSums, int* __restrict__ blockOffsets,
        int* __restrict__ rowStartN, int nB) {
    __shared__ int wtot[4];
    int tid = threadIdx.x, lane = tid & 63, wid = tid >> 6;
    int v = (tid < nB) ? blockSums[tid] : 0;
    int x = v;
    #pragma unroll
    for (int off = 1; off < 64; off <<= 1) { int y = __shfl_up(x, off, 64); if (lane >= off) x += y; }
    if (lane == 63) wtot[wid] = x;
    __syncthreads();
    int woff = 0;
    for (int w = 0; w < wid; ++w) woff += wtot[w];
    if (tid < nB) blockOffsets[tid] = woff + x - v;
    if (tid == 255) rowStartN[0] = woff + x;   // grand total = E
}

// NOTE: cursor may alias counts — every thread reads its 4 counts into
// registers before any write, and element ownership is 1 thread : 4 elems.
__global__ __launch_bounds__(256) void scan_final(
        const int* __restrict__ counts, const int* __restrict__ blockOffsets,
        int* __restrict__ rowStart, int* __restrict__ cursor, int n) {
    __shared__ int wtot[4];
    int tid = threadIdx.x, lane = tid & 63, wid = tid >> 6;
    int base = blockIdx.x * CHUNK + tid * 4;
    int v0 = (base + 0 < n) ? counts[base + 0] : 0;
    int v1 = (base + 1 < n) ? counts[base + 1] : 0;
    int v2 = (base + 2 < n) ? counts[base + 2] : 0;
    int v3 = (base + 3 < n) ? counts[base + 3] : 0;
    int t = v0 + v1 + v2 + v3;
    int x = t;
    #pragma unroll
    for (int off = 1; off < 64; off <<= 1) { int y = __shfl_up(x, off, 64); if (lane >= off) x += y; }
    if (lane == 63) wtot[wid] = x;
    __syncthreads();
    int woff = 0;
    for (int w = 0; w < wid; ++w) woff += wtot[w];
    int e = blockOffsets[blockIdx.x] + woff + (x - t);
    if (base + 0 < n) { rowStart[base + 0] = e; cursor[base + 0] = e; } e += v0;
    if (base + 1 < n) { rowStart[base + 1] = e; cursor[base + 1] = e; } e += v1;
    if (base + 2 < n) { rowStart[base + 2] = e; cursor[base + 2] = e; } e += v2;
    if (base + 3 < n) { rowStart[base + 3] = e; cursor[base + 3] = e; }
}

__global__ __launch_bounds__(256) void edge_fill(
        const void* __restrict__ eidx, const int* __restrict__ flagp,
        int* __restrict__ cursor, int* __restrict__ srcs, int nE) {
    const bool idx64 = (*flagp != 0);
    const int* __restrict__ ei32 = (const int*)eidx;
    const long long* __restrict__ ei64 = (const long long*)eidx;
    int i = blockIdx.x * blockDim.x + threadIdx.x;
    int stride = gridDim.x * blockDim.x;
    for (int e = i; e < nE; e += stride) {
        int s, d;
        if (idx64) { s = (int)ei64[e]; d = (int)ei64[e + nE]; }
        else       { s = ei32[e];      d = ei32[e + nE]; }
        int pos = atomicAdd(&cursor[d], 1);
        srcs[pos] = s;
    }
}

// ---------------- layer stage 1: gather + mean (latency-optimized) ---------
// 16 nodes per block; each 16-lane group owns one node, lane = 4-feature chunk.
// No LDS, tiny VGPR -> max occupancy; unroll-2 -> 2 outstanding 256B row loads
// per group (8 per wave).
__global__ __launch_bounds__(256) void gather_mean(
        const float* __restrict__ x,
        const int* __restrict__ rowStart,
        const int* __restrict__ srcs,
        float* __restrict__ agg,
        int nNodes) {
    const int tid = threadIdx.x;
    const int gl = tid & 15;          // lane within group (feature chunk)
    const int grp = tid >> 4;         // group within block (node)
    const int node = blockIdx.x * 16 + grp;
    if (node >= nNodes) return;
    const int r0 = rowStart[node], r1 = rowStart[node + 1];
    float ax = 0.f, ay = 0.f, az = 0.f, aw = 0.f;
    int j = r0;
    for (; j + 2 <= r1; j += 2) {
        int s0 = srcs[j], s1 = srcs[j + 1];
        float4 v0 = *(const float4*)&x[(size_t)s0 * D + gl * 4];
        float4 v1 = *(const float4*)&x[(size_t)s1 * D + gl * 4];
        ax += v0.x; ay += v0.y; az += v0.z; aw += v0.w;
        ax += v1.x; ay += v1.y; az += v1.z; aw += v1.w;
    }
    if (j < r1) {
        int s = srcs[j];
        float4 v = *(const float4*)&x[(size_t)s * D + gl * 4];
        ax += v.x; ay += v.y; az += v.z; aw += v.w;
    }
    const float inv = 1.0f / fmaxf((float)(r1 - r0), 1.0f);
    float4 o; o.x = ax * inv; o.y = ay * inv; o.z = az * inv; o.w = aw * inv;
    *(float4*)&agg[(size_t)node * D + gl * 4] = o;
}

// ---------------- layer stage 2: register-blocked f32 GEMM update ----------
// Block = GN(128) nodes x 64 features, 256 threads, 8x4 per-thread tile.
// Two sequential phases share LDS: (agg @ wl^T) then (x @ wr^T), accumulate.
// sA holds A^T [k][n] (pad 4 -> staging writes 8-way worst case, reads clean);
// sW holds W^T [k][f].
__global__ __launch_bounds__(256) void gemm_update(
        const float* __restrict__ agg,
        const float* __restrict__ xin,
        const float* __restrict__ wl,
        const float* __restrict__ bl,
        const float* __restrict__ wr,
        float* __restrict__ xout,
        int nNodes, int mode) {
    __shared__ float sA[D][GN + 4];
    __shared__ float sW[D][D + 4];
    const int tid = threadIdx.x;
    const int fx = tid & 15, nx = tid >> 4;
    const int f0 = fx * 4, n0 = nx * 8;
    const int nb = blockIdx.x * GN;

    float c[8][4];
    #pragma unroll
    for (int i = 0; i < 8; ++i)
        #pragma unroll
        for (int j = 0; j < 4; ++j) c[i][j] = 0.f;

    #pragma unroll
    for (int phase = 0; phase < 2; ++phase) {
        const float* __restrict__ gA = phase ? xin : agg;
        const float* __restrict__ gW = phase ? wr : wl;
        if (phase) __syncthreads();           // previous K-loop reads done
        for (int i = tid; i < GN * D; i += 256) {
            int n = i >> 6, k = i & 63;
            int gn = nb + n;
            sA[k][n] = (gn < nNodes) ? gA[(size_t)gn * D + k] : 0.f;
        }
        for (int i = tid; i < D * D; i += 256) {
            int f = i >> 6, k = i & 63;
            sW[k][f] = gW[i];
        }
        __syncthreads();
        #pragma unroll 8
        for (int k = 0; k < D; ++k) {
            float4 a0 = *(const float4*)&sA[k][n0];
            float4 a1 = *(const float4*)&sA[k][n0 + 4];
            float4 w  = *(const float4*)&sW[k][f0];
            float av[8] = {a0.x, a0.y, a0.z, a0.w, a1.x, a1.y, a1.z, a1.w};
            float wv[4] = {w.x, w.y, w.z, w.w};
            #pragma unroll
            for (int i = 0; i < 8; ++i)
                #pragma unroll
                for (int j = 0; j < 4; ++j)
                    c[i][j] = fmaf(av[i], wv[j], c[i][j]);
        }
    }

    float4 bv = *(const float4*)&bl[f0];
    float blv[4] = {bv.x, bv.y, bv.z, bv.w};
    #pragma unroll
    for (int i = 0; i < 8; ++i) {
        int gn = nb + n0 + i;
        float o[4];
        #pragma unroll
        for (int j = 0; j < 4; ++j) o[j] = c[i][j] + blv[j];
        if (mode == 0) {
            #pragma unroll
            for (int j = 0; j < 4; ++j) o[j] = fmaxf(o[j], 0.f);
        } else {
            float ss = o[0]*o[0] + o[1]*o[1] + o[2]*o[2] + o[3]*o[3];
            #pragma unroll
            for (int off = 8; off >= 1; off >>= 1) ss += __shfl_xor(ss, off, 16);
            float inv = 1.0f / fmaxf(sqrtf(ss), 1e-12f);
            #pragma unroll
            for (int j = 0; j < 4; ++j) o[j] *= inv;
        }
        if (gn < nNodes) {
            float4 ov; ov.x = o[0]; ov.y = o[1]; ov.z = o[2]; ov.w = o[3];
            *(float4*)&xout[(size_t)gn * D + f0] = ov;
        }
    }
}

// ---------------- fallback: atomic scatter path (round-1, known-correct) ----

__global__ __launch_bounds__(256) void sage_scatter(
        const float* __restrict__ x,
        const void* __restrict__ eidx,
        const int* __restrict__ flagp,
        float* __restrict__ agg,
        float* __restrict__ deg,
        int nE, int doDeg) {
    const bool idx64 = (*flagp != 0);
    const int lane = threadIdx.x & 63;
    int wave = (int)((blockIdx.x * blockDim.x + threadIdx.x) >> 6);
    const int waveStride = (int)((gridDim.x * blockDim.x) >> 6);
    const int* __restrict__ ei32 = (const int*)eidx;
    const long long* __restrict__ ei64 = (const long long*)eidx;
    for (int e = wave; e < nE; e += waveStride) {
        int s, d;
        if (idx64) { s = (int)ei64[e]; d = (int)ei64[e + nE]; }
        else       { s = ei32[e];      d = ei32[e + nE]; }
        atomicAdd(&agg[(size_t)d * D + lane], x[(size_t)s * D + lane]);
        if (doDeg && lane == 0) atomicAdd(&deg[d], 1.0f);
    }
}

__global__ __launch_bounds__(256) void sage_update(
        const float* __restrict__ xin,
        const float* __restrict__ agg,
        const float* __restrict__ deg,
        const float* __restrict__ wl,
        const float* __restrict__ bl,
        const float* __restrict__ wr,
        float* __restrict__ xout,
        int nNodes, int mode) {
    __shared__ float wlT[D * D];
    __shared__ float wrT[D * D];
    __shared__ float rowA[4][D];
    __shared__ float rowX[4][D];
    for (int i = threadIdx.x; i < D * D; i += blockDim.x) {
        int f = i >> 6, k = i & 63;
        wlT[k * D + f] = wl[i];
        wrT[k * D + f] = wr[i];
    }
    __syncthreads();
    const int lane = threadIdx.x & 63;
    const int wid = threadIdx.x >> 6;
    const float blv = bl[lane];
    for (int node = blockIdx.x * 4 + wid; node < nNodes; node += gridDim.x * 4) {
        float dg = fmaxf(deg[node], 1.0f);
        float a  = agg[(size_t)node * D + lane] / dg;
        float xv = xin[(size_t)node * D + lane];
        rowA[wid][lane] = a;
        rowX[wid][lane] = xv;
        float acc = blv;
        #pragma unroll
        for (int k = 0; k < D; ++k) {
            acc = fmaf(rowA[wid][k], wlT[k * D + lane], acc);
            acc = fmaf(rowX[wid][k], wrT[k * D + lane], acc);
        }
        if (mode == 0) {
            xout[(size_t)node * D + lane] = fmaxf(acc, 0.0f);
        } else {
            float ss = acc * acc;
            #pragma unroll
            for (int off = 32; off >= 1; off >>= 1) ss += __shfl_xor(ss, off, 64);
            xout[(size_t)node * D + lane] = acc / fmaxf(sqrtf(ss), 1e-12f);
        }
    }
}

extern "C" void kernel_launch(void* const* d_in, const int* in_sizes, int n_in,
                              void* d_out, int out_size, void* d_ws, size_t ws_size,
                              hipStream_t stream) {
    const float* x   = (const float*)d_in[0];
    const float* wl0 = (const float*)d_in[1];
    const float* bl0 = (const float*)d_in[2];
    const float* wr0 = (const float*)d_in[3];
    const float* wl1 = (const float*)d_in[4];
    const float* bl1 = (const float*)d_in[5];
    const float* wr1 = (const float*)d_in[6];
    const void*  ei  = d_in[7];
    float* out = (float*)d_out;

    const int N = in_sizes[0] / D;
    const int E = in_sizes[7] / 2;
    const int nB = (N + CHUNK - 1) / CHUNK;   // 98 for N=100000 (<=256 required)

    char* ws = (char*)d_ws;
    size_t off = 0;
    auto alloc = [&](size_t bytes) { void* p = ws + off; off = (off + bytes + 255) & ~(size_t)255; return p; };

    size_t need = 0;
    {
        size_t o = 0;
        auto sim = [&](size_t b) { o = (o + b + 255) & ~(size_t)255; };
        sim(4); sim((size_t)N * 4); sim(((size_t)N + 1) * 4);
        sim(256 * 4); sim(256 * 4); sim((size_t)E * 4);
        sim((size_t)N * D * 4); sim((size_t)N * D * 4);
        need = o;
    }

    if (ws_size >= need && nB <= 256) {
        int* flag         = (int*)alloc(4);
        int* counts       = (int*)alloc((size_t)N * 4);
        int* rowStart     = (int*)alloc(((size_t)N + 1) * 4);
        int* blockSums    = (int*)alloc(256 * 4);
        int* blockOffsets = (int*)alloc(256 * 4);
        int* srcs         = (int*)alloc((size_t)E * 4);
        float* x1         = (float*)alloc((size_t)N * D * 4);
        float* agg        = (float*)alloc((size_t)N * D * 4);
        int* cursor = counts;   // aliased: counts dead after scan_final reads

        detect_idx64<<<1, 64, 0, stream>>>((const int*)ei, flag);
        hipMemsetAsync(counts, 0, (size_t)N * 4, stream);
        edge_hist<<<2048, 256, 0, stream>>>(ei, flag, counts, E);
        scan_partial<<<nB, 256, 0, stream>>>(counts, blockSums, N);
        scan_block<<<1, 256, 0, stream>>>(blockSums, blockOffsets, &rowStart[N], nB);
        scan_final<<<nB, 256, 0, stream>>>(counts, blockOffsets, rowStart, cursor, N);
        edge_fill<<<2048, 256, 0, stream>>>(ei, flag, cursor, srcs, E);

        const int gGather = (N + 15) / 16;
        const int gGemm   = (N + GN - 1) / GN;
        gather_mean<<<gGather, 256, 0, stream>>>(x, rowStart, srcs, agg, N);
        gemm_update<<<gGemm, 256, 0, stream>>>(agg, x, wl0, bl0, wr0, x1, N, 0);
        gather_mean<<<gGather, 256, 0, stream>>>(x1, rowStart, srcs, agg, N);
        gemm_update<<<gGemm, 256, 0, stream>>>(agg, x1, wl1, bl1, wr1, out, N, 1);
    } else {
        // fallback: round-1 scatter path (~26 MB ws)
        int*   flag = (int*)alloc(4);
        float* deg  = (float*)alloc((size_t)N * 4);
        float* agg  = (float*)alloc((size_t)N * D * 4);
        float* x1   = out;  // safe: sage_update reads only its own row of xin

        detect_idx64<<<1, 64, 0, stream>>>((const int*)ei, flag);
        hipMemsetAsync(deg, 0, ((size_t)N + (size_t)N * D) * 4, stream);
        sage_scatter<<<4096, 256, 0, stream>>>(x, ei, flag, agg, deg, E, 1);
        sage_update<<<2048, 256, 0, stream>>>(x, agg, deg, wl0, bl0, wr0, x1, N, 0);
        hipMemsetAsync(agg, 0, (size_t)N * D * 4, stream);
        sage_scatter<<<4096, 256, 0, stream>>>(x1, ei, flag, agg, deg, E, 0);
        sage_update<<<2048, 256, 0, stream>>>(x1, agg, deg, wl1, bl1, wr1, out, N, 1);
    }
}